// Round 16
// baseline (46.062 us; speedup 1.0000x reference)
//
#include <hip/hip_runtime.h>
#include <hip/hip_bf16.h>

#define TSEQ   4096
#define NB     4
#define EMB    512
#define HS     32
#define NQ     16384      // NB * TSEQ

typedef float  f32x4  __attribute__((ext_vector_type(4)));
typedef __bf16 bf16x8 __attribute__((ext_vector_type(8)));
typedef __bf16 bf16x4 __attribute__((ext_vector_type(4)));

// ---------------------------------------------------------------------------
// R16 = R15 (43.3us) with the attn inner loop converted to 2-TILE ILP:
// each iteration processes two independent 32-key tiles (separate K/V regs,
// separate P buffers, independent S->exp->pack->PV chains) so one chain's
// stalls are covered by the other's issue.  Measured basis: attn ~3000cy/tile
// wall vs ~200cy issue (7x stall factor); extra WAVES failed (R10) but
// within-wave ILP shares no barrier/occupancy cost.  Tile accumulation order
// unchanged -> bit-identical output.
// ---------------------------------------------------------------------------

// ---------------------------------------------------------------------------
// Kernel 1: MFMA QKV projection, split-K x4, weights inlined from fp32.
// (R13/R15, unchanged — measured ~9.5us, near x-read latency floor)
// ---------------------------------------------------------------------------
__global__ __launch_bounds__(256) void qkv_mfma(
    const float* __restrict__ x,
    const float* __restrict__ Wq, const float* __restrict__ bq,
    const float* __restrict__ Wk, const float* __restrict__ bk,
    const float* __restrict__ Wv, const float* __restrict__ bv,
    __bf16* __restrict__ qbf, __bf16* __restrict__ kbf, __bf16* __restrict__ vtb)
{
    const int tid  = threadIdx.x;
    const int lane = tid & 63;
    const int w    = tid >> 6;        // 0..3 (K-quarter)
    const int lr = lane & 15;
    const int lh = lane >> 4;
    const int tok0 = blockIdx.x * 16;
    const int k0   = w * 128;

    const float qs = 0.17677669529663687f;   // 1/sqrt(32)
    const float* xp = x + (size_t)(tok0 + lr) * EMB + k0 + lh * 8;

    const float* wbase[6] = { Wq + lr, Wq + 16 + lr,
                              Wk + lr, Wk + 16 + lr,
                              Wv + lr, Wv + 16 + lr };

    auto ldfrag = [&](int f, int koff) -> bf16x8 {
        const float* p = wbase[f] + (size_t)(k0 + koff + lh * 8) * HS;
        const float s = (f < 2) ? qs : 1.0f;
        bf16x8 r;
        #pragma unroll
        for (int j = 0; j < 8; ++j)
            r[j] = (__bf16)(p[(size_t)j * HS] * s);
        return r;
    };
    auto ldx = [&](int koff) -> bf16x8 {
        const float4 a4 = *(const float4*)(xp + koff);
        const float4 b4 = *(const float4*)(xp + koff + 4);
        return bf16x8{ (__bf16)a4.x, (__bf16)a4.y, (__bf16)a4.z, (__bf16)a4.w,
                       (__bf16)b4.x, (__bf16)b4.y, (__bf16)b4.z, (__bf16)b4.w };
    };

    const f32x4 z = {0.f, 0.f, 0.f, 0.f};
    f32x4 acc[6] = {z, z, z, z, z, z};   // aq0,aq1,ak0,ak1,av0,av1

    bf16x8 xf_c, wf_c[6], xf_n, wf_n[6];
    xf_c = ldx(0);
    #pragma unroll
    for (int f = 0; f < 6; ++f) wf_c[f] = ldfrag(f, 0);

    #pragma unroll
    for (int kt = 0; kt < 128; kt += 32) {
        const int ktn = (kt + 32 < 128) ? (kt + 32) : kt;
        xf_n = ldx(ktn);
        #pragma unroll
        for (int f = 0; f < 6; ++f) wf_n[f] = ldfrag(f, ktn);

        acc[0] = __builtin_amdgcn_mfma_f32_16x16x32_bf16(wf_c[0], xf_c, acc[0], 0, 0, 0);
        acc[1] = __builtin_amdgcn_mfma_f32_16x16x32_bf16(wf_c[1], xf_c, acc[1], 0, 0, 0);
        acc[2] = __builtin_amdgcn_mfma_f32_16x16x32_bf16(wf_c[2], xf_c, acc[2], 0, 0, 0);
        acc[3] = __builtin_amdgcn_mfma_f32_16x16x32_bf16(wf_c[3], xf_c, acc[3], 0, 0, 0);
        acc[4] = __builtin_amdgcn_mfma_f32_16x16x32_bf16(xf_c, wf_c[4], acc[4], 0, 0, 0);
        acc[5] = __builtin_amdgcn_mfma_f32_16x16x32_bf16(xf_c, wf_c[5], acc[5], 0, 0, 0);

        xf_c = xf_n;
        #pragma unroll
        for (int f = 0; f < 6; ++f) wf_c[f] = wf_n[f];
    }

    __shared__ float red[3 * 6 * 256];
    if (w > 0) {
        #pragma unroll
        for (int i = 0; i < 6; ++i)
            *(f32x4*)&red[((w - 1) * 6 + i) * 256 + lane * 4] = acc[i];
    }
    __syncthreads();
    if (w != 0) return;

    #pragma unroll
    for (int i = 0; i < 6; ++i)
        #pragma unroll
        for (int ww = 0; ww < 3; ++ww)
            acc[i] += *(const f32x4*)&red[(ww * 6 + i) * 256 + lane * 4];

    #pragma unroll
    for (int f = 0; f < 2; ++f) {
        const int cb = f * 16 + lh * 4;
        const float4 bq4 = *(const float4*)(bq + cb);
        const float4 bk4 = *(const float4*)(bk + cb);
        bf16x4 oq = { (__bf16)(acc[f][0] + bq4.x * qs), (__bf16)(acc[f][1] + bq4.y * qs),
                      (__bf16)(acc[f][2] + bq4.z * qs), (__bf16)(acc[f][3] + bq4.w * qs) };
        bf16x4 ok = { (__bf16)(acc[2+f][0] + bk4.x), (__bf16)(acc[2+f][1] + bk4.y),
                      (__bf16)(acc[2+f][2] + bk4.z), (__bf16)(acc[2+f][3] + bk4.w) };
        *(bf16x4*)(qbf + (size_t)(tok0 + lr) * HS + cb) = oq;
        *(bf16x4*)(kbf + (size_t)(tok0 + lr) * HS + cb) = ok;
    }
    {
        const int b    = tok0 >> 12;
        const int t_in = (tok0 & (TSEQ - 1)) + lh * 4;
        #pragma unroll
        for (int f = 0; f < 2; ++f) {
            const int d = f * 16 + lr;
            const float bv1 = bv[d];
            bf16x4 o = { (__bf16)(acc[4+f][0] + bv1), (__bf16)(acc[4+f][1] + bv1),
                         (__bf16)(acc[4+f][2] + bv1), (__bf16)(acc[4+f][3] + bv1) };
            *(bf16x4*)(vtb + ((size_t)(b * HS + d)) * TSEQ + t_in) = o;
        }
    }
}

// ---------------------------------------------------------------------------
// Kernel 2: FUSED attention + projection, 2-tile-ILP inner loop.
// ---------------------------------------------------------------------------
__device__ __forceinline__ void s_stage2(
    const bf16x8 ck0, const bf16x8 ck1,
    const bf16x8 qb0, const bf16x8 qb1,
    int kt, int q0, int lr, int lh, int swz,
    float lp[2], char* Pb)
{
    const f32x4 z = {0.f, 0.f, 0.f, 0.f};
    __builtin_amdgcn_s_setprio(1);
    f32x4 st00 = __builtin_amdgcn_mfma_f32_16x16x32_bf16(ck0, qb0, z, 0, 0, 0);
    f32x4 st01 = __builtin_amdgcn_mfma_f32_16x16x32_bf16(ck1, qb0, z, 0, 0, 0);
    f32x4 st10 = __builtin_amdgcn_mfma_f32_16x16x32_bf16(ck0, qb1, z, 0, 0, 0);
    f32x4 st11 = __builtin_amdgcn_mfma_f32_16x16x32_bf16(ck1, qb1, z, 0, 0, 0);
    __builtin_amdgcn_s_setprio(0);

    float P[2][2][4];   // [qh][kh][r]; key_l = kh*16+lh*4+r, q_l = qh*16+lr
    #pragma unroll
    for (int r = 0; r < 4; ++r) {
        P[0][0][r] = st00[r]; P[0][1][r] = st01[r];
        P[1][0][r] = st10[r]; P[1][1][r] = st11[r];
    }

    if (kt != q0) {
        #pragma unroll
        for (int qh = 0; qh < 2; ++qh)
            #pragma unroll
            for (int kh = 0; kh < 2; ++kh)
                #pragma unroll
                for (int r = 0; r < 4; ++r)
                    P[qh][kh][r] = __expf(P[qh][kh][r]);
    } else {
        #pragma unroll
        for (int qh = 0; qh < 2; ++qh)
            #pragma unroll
            for (int kh = 0; kh < 2; ++kh)
                #pragma unroll
                for (int r = 0; r < 4; ++r) {
                    const int key_l = kh * 16 + lh * 4 + r;
                    const int q_l   = qh * 16 + lr;
                    P[qh][kh][r] = (key_l <= q_l) ? __expf(P[qh][kh][r]) : 0.f;
                }
    }

    #pragma unroll
    for (int qh = 0; qh < 2; ++qh)
        #pragma unroll
        for (int kh = 0; kh < 2; ++kh)
            #pragma unroll
            for (int r = 0; r < 4; ++r)
                lp[qh] += P[qh][kh][r];

    #pragma unroll
    for (int qh = 0; qh < 2; ++qh)
        #pragma unroll
        for (int kh = 0; kh < 2; ++kh) {
            const int q    = qh * 16 + lr;
            const int byte = q * 128 + ((kh * 32 + lh * 8) ^ swz);
            bf16x4 pk = { (__bf16)P[qh][kh][0], (__bf16)P[qh][kh][1],
                          (__bf16)P[qh][kh][2], (__bf16)P[qh][kh][3] };
            *(bf16x4*)(Pb + byte) = pk;
        }
}

// 2-tile-ILP strip processor: tiles kt0, kt0+256, ... < kend processed in
// pairs (A,B) with independent chains; next pair prefetched one pair ahead.
__device__ __forceinline__ void strip_dual(
    int kt0, int kend, int q0,
    const bf16x8 qb0, const bf16x8 qb1,
    const __bf16* kbase, const __bf16* vbase,
    char* Pl,                         // 8KB: bufA @0, bufB @4096
    f32x4 o[4], float lp[2],
    int lr, int lh, int swz, int rdA, int rdB)
{
    if (kt0 >= kend) return;

    int ktA = kt0;
    int ktB = kt0 + 256;
    bool hasB = (ktB < kend);

    bf16x8 ka0 = *(const bf16x8*)(kbase + (size_t)ktA * HS);
    bf16x8 ka1 = *(const bf16x8*)(kbase + (size_t)(ktA + 16) * HS);
    bf16x8 va0 = *(const bf16x8*)(vbase + ktA);
    bf16x8 va1 = *(const bf16x8*)(vbase + ktA + 16 * TSEQ);
    const int kB0 = hasB ? ktB : ktA;
    bf16x8 kb0 = *(const bf16x8*)(kbase + (size_t)kB0 * HS);
    bf16x8 kb1 = *(const bf16x8*)(kbase + (size_t)(kB0 + 16) * HS);
    bf16x8 vb0 = *(const bf16x8*)(vbase + kB0);
    bf16x8 vb1 = *(const bf16x8*)(vbase + kB0 + 16 * TSEQ);

    for (;;) {
        const int ktA2 = ktA + 512, ktB2 = ktB + 512;
        const bool moreA = (ktA2 < kend);
        const bool moreB = (ktB2 < kend);
        const int pA = moreA ? ktA2 : ktA;       // clamped prefetch (harmless)
        const int pB = moreB ? ktB2 : ktA;
        bf16x8 nka0 = *(const bf16x8*)(kbase + (size_t)pA * HS);
        bf16x8 nka1 = *(const bf16x8*)(kbase + (size_t)(pA + 16) * HS);
        bf16x8 nva0 = *(const bf16x8*)(vbase + pA);
        bf16x8 nva1 = *(const bf16x8*)(vbase + pA + 16 * TSEQ);
        bf16x8 nkb0 = *(const bf16x8*)(kbase + (size_t)pB * HS);
        bf16x8 nkb1 = *(const bf16x8*)(kbase + (size_t)(pB + 16) * HS);
        bf16x8 nvb0 = *(const bf16x8*)(vbase + pB);
        bf16x8 nvb1 = *(const bf16x8*)(vbase + pB + 16 * TSEQ);

        // two independent S-stages into separate buffers
        s_stage2(ka0, ka1, qb0, qb1, ktA, q0, lr, lh, swz, lp, Pl);
        if (hasB)
            s_stage2(kb0, kb1, qb0, qb1, ktB, q0, lr, lh, swz, lp, Pl + 4096);

        // PV A (tile order preserved: A before B)
        {
            const bf16x8 pa0 = *(const bf16x8*)(Pl + rdA);
            const bf16x8 pa1 = *(const bf16x8*)(Pl + rdB);
            __builtin_amdgcn_s_setprio(1);
            o[0] = __builtin_amdgcn_mfma_f32_16x16x32_bf16(pa0, va0, o[0], 0, 0, 0);
            o[1] = __builtin_amdgcn_mfma_f32_16x16x32_bf16(pa0, va1, o[1], 0, 0, 0);
            o[2] = __builtin_amdgcn_mfma_f32_16x16x32_bf16(pa1, va0, o[2], 0, 0, 0);
            o[3] = __builtin_amdgcn_mfma_f32_16x16x32_bf16(pa1, va1, o[3], 0, 0, 0);
            __builtin_amdgcn_s_setprio(0);
        }
        if (hasB) {
            const bf16x8 pb0 = *(const bf16x8*)(Pl + 4096 + rdA);
            const bf16x8 pb1 = *(const bf16x8*)(Pl + 4096 + rdB);
            __builtin_amdgcn_s_setprio(1);
            o[0] = __builtin_amdgcn_mfma_f32_16x16x32_bf16(pb0, vb0, o[0], 0, 0, 0);
            o[1] = __builtin_amdgcn_mfma_f32_16x16x32_bf16(pb0, vb1, o[1], 0, 0, 0);
            o[2] = __builtin_amdgcn_mfma_f32_16x16x32_bf16(pb1, vb0, o[2], 0, 0, 0);
            o[3] = __builtin_amdgcn_mfma_f32_16x16x32_bf16(pb1, vb1, o[3], 0, 0, 0);
            __builtin_amdgcn_s_setprio(0);
        }

        if (!moreA) break;
        ktA = ktA2; ktB = ktB2; hasB = moreB;
        ka0 = nka0; ka1 = nka1; va0 = nva0; va1 = nva1;
        kb0 = nkb0; kb1 = nkb1; vb0 = nvb0; vb1 = nvb1;
    }
}

__global__ __launch_bounds__(512) void attn_fused(
    const __bf16* __restrict__ qbf, const __bf16* __restrict__ kbf,
    const __bf16* __restrict__ vtb,
    const float* __restrict__ Wp, const float* __restrict__ bp,
    float* __restrict__ out)
{
    const int p   = blockIdx.x;       // strips p and 127-p
    const int b   = blockIdx.y;
    const int tid = threadIdx.x;
    const int w    = tid >> 6;        // 0..7
    const int lane = tid & 63;
    const int lr = lane & 15;
    const int lh = lane >> 4;

    const int n0  = p + 1;
    const int q00 = p * 32;
    const int q01 = (127 - p) * 32;

    extern __shared__ char smem[];
    char*   myPl   = smem + w * 8192;
    float*  red    = (float*)smem;
    float*  lpred  = (float*)(smem + 65536);
    __bf16* attn_s = (__bf16*)(smem + 65536 + 2048);

    const __bf16* qp0 = qbf + ((size_t)(b * TSEQ + q00 + lr)) * HS + lh * 8;
    const __bf16* qp1 = qbf + ((size_t)(b * TSEQ + q01 + lr)) * HS + lh * 8;
    const bf16x8 qb0s0 = *(const bf16x8*)qp0;
    const bf16x8 qb1s0 = *(const bf16x8*)(qp0 + 16 * HS);
    const bf16x8 qb0s1 = *(const bf16x8*)qp1;
    const bf16x8 qb1s1 = *(const bf16x8*)(qp1 + 16 * HS);

    const __bf16* kbase = kbf + ((size_t)(b * TSEQ + lr)) * HS + lh * 8;
    const __bf16* vbase = vtb + (size_t)(b * HS + lr) * TSEQ + lh * 8;

    const int swz = (lr & 7) << 4;
    const int rdA = lr * 128 + ((lh * 16) ^ swz);
    const int rdB = (16 + lr) * 128 + ((lh * 16) ^ swz);

    const f32x4 z = {0.f, 0.f, 0.f, 0.f};
    f32x4 o0[4] = {z, z, z, z};
    f32x4 o1[4] = {z, z, z, z};
    float lp0[2] = {0.f, 0.f}, lp1[2] = {0.f, 0.f};

    strip_dual(w * 32, q00 + 32, q00, qb0s0, qb1s0, kbase, vbase, myPl,
               o0, lp0, lr, lh, swz, rdA, rdB);
    const int tb = n0 + ((w - n0) & 7);
    strip_dual((tb - n0) * 32, q01 + 32, q01, qb0s1, qb1s1, kbase, vbase, myPl,
               o1, lp1, lr, lh, swz, rdA, rdB);

    #pragma unroll
    for (int qh = 0; qh < 2; ++qh) {
        lp0[qh] += __shfl_xor(lp0[qh], 16, 64);
        lp0[qh] += __shfl_xor(lp0[qh], 32, 64);
        lp1[qh] += __shfl_xor(lp1[qh], 16, 64);
        lp1[qh] += __shfl_xor(lp1[qh], 32, 64);
    }

    __syncthreads();

    #pragma unroll
    for (int f = 0; f < 4; ++f) {
        *(f32x4*)&red[((w * 2 + 0) * 4 + f) * 256 + lane * 4] = o0[f];
        *(f32x4*)&red[((w * 2 + 1) * 4 + f) * 256 + lane * 4] = o1[f];
    }
    if (lh == 0) {
        #pragma unroll
        for (int qh = 0; qh < 2; ++qh) {
            lpred[(w * 2 + 0) * 32 + qh * 16 + lr] = lp0[qh];
            lpred[(w * 2 + 1) * 32 + qh * 16 + lr] = lp1[qh];
        }
    }
    __syncthreads();

    {
        const int s  = w >> 2;
        const int f  = w & 3;
        const int qh = f >> 1;
        const int dh = f & 1;
        f32x4 sum = z;
        #pragma unroll
        for (int ww = 0; ww < 8; ++ww)
            sum += *(const f32x4*)&red[((ww * 2 + s) * 4 + f) * 256 + lane * 4];

        #pragma unroll
        for (int r = 0; r < 4; ++r) {
            const int q = qh * 16 + lh * 4 + r;
            float L = 0.f;
            #pragma unroll
            for (int ww = 0; ww < 8; ++ww)
                L += lpred[(ww * 2 + s) * 32 + q];
            attn_s[(s * 32 + q) * 32 + dh * 16 + lr] = (__bf16)(sum[r] / L);
        }
    }
    __syncthreads();

    // projection (SWAPPED): wave w -> strip sp = w>>2, cols [(w&3)*128, +128)
    {
        const int sp = w >> 2;
        const int c0 = (w & 3) * 128;
        const int qb0i = (sp == 0) ? q00 : q01;
        const __bf16* as = attn_s + sp * 1024;
        const bf16x8 a0 = *(const bf16x8*)(as + lr * 32 + lh * 8);
        const bf16x8 a1 = *(const bf16x8*)(as + (16 + lr) * 32 + lh * 8);

        #pragma unroll
        for (int g = 0; g < 8; ++g) {
            const int c = c0 + g * 16;
            const float* wsrc = Wp + (size_t)(lh * 8) * EMB + c + lr;
            bf16x8 wa;
            #pragma unroll
            for (int j = 0; j < 8; ++j)
                wa[j] = (__bf16)wsrc[(size_t)j * EMB];

            f32x4 d0 = __builtin_amdgcn_mfma_f32_16x16x32_bf16(wa, a0, z, 0, 0, 0);
            f32x4 d1 = __builtin_amdgcn_mfma_f32_16x16x32_bf16(wa, a1, z, 0, 0, 0);

            const float4 b4 = *(const float4*)(bp + c + lh * 4);
            const float4 ov0 = make_float4(d0[0] + b4.x, d0[1] + b4.y,
                                           d0[2] + b4.z, d0[3] + b4.w);
            const float4 ov1 = make_float4(d1[0] + b4.x, d1[1] + b4.y,
                                           d1[2] + b4.z, d1[3] + b4.w);
            *(float4*)(out + (size_t)(b * TSEQ + qb0i + lr)      * EMB + c + lh * 4) = ov0;
            *(float4*)(out + (size_t)(b * TSEQ + qb0i + 16 + lr) * EMB + c + lh * 4) = ov1;
        }
    }
}

// ---------------------------------------------------------------------------
extern "C" void kernel_launch(void* const* d_in, const int* in_sizes, int n_in,
                              void* d_out, int out_size, void* d_ws, size_t ws_size,
                              hipStream_t stream)
{
    const float* x  = (const float*)d_in[0];
    const float* Wq = (const float*)d_in[1];
    const float* bq = (const float*)d_in[2];
    const float* Wk = (const float*)d_in[3];
    const float* bk = (const float*)d_in[4];
    const float* Wv = (const float*)d_in[5];
    const float* bv = (const float*)d_in[6];
    const float* Wp = (const float*)d_in[7];
    const float* bp = (const float*)d_in[8];
    float* out = (float*)d_out;

    // workspace: qbf @0 (1MB), kbf @1MB (1MB), vtb @2MB (1MB)
    char* ws = (char*)d_ws;
    __bf16* qbf = (__bf16*)(ws);
    __bf16* kbf = (__bf16*)(ws + (size_t)1 * 1024 * 1024);
    __bf16* vtb = (__bf16*)(ws + (size_t)2 * 1024 * 1024);

    qkv_mfma<<<dim3(NQ / 16), 256, 0, stream>>>(x, Wq, bq, Wk, bk, Wv, bv,
                                                qbf, kbf, vtb);
    attn_fused<<<dim3(64, NB), 512, 71680, stream>>>(qbf, kbf, vtb, Wp, bp, out);
}

// Round 17
// 43.211 us; speedup vs baseline: 1.0660x; 1.0660x over previous
//
#include <hip/hip_runtime.h>
#include <hip/hip_bf16.h>

#define TSEQ   4096
#define NB     4
#define EMB    512
#define HS     32
#define NQ     16384      // NB * TSEQ

typedef float  f32x4  __attribute__((ext_vector_type(4)));
typedef __bf16 bf16x8 __attribute__((ext_vector_type(8)));
typedef __bf16 bf16x4 __attribute__((ext_vector_type(4)));

// ---------------------------------------------------------------------------
// R17 = R15 verbatim — the measured session optimum (43.29us).
// R16's 2-tile ILP REVERTED (46.1us: doubled live K/V/P register state pushed
// past the pressure knee; chains serialized anyway).
// Final decomposition (measured, R11/R12 probes): ~13us fixed harness/graph
// overhead + ~9.5us qkv (x-read latency floor; 3 structural variants tied)
// + ~20.5us attn (dependency-stall floor for this structure; LDS-free PV,
// pipelining, 2x TLP, setprio, 2-tile ILP all neutral-or-negative).
// ---------------------------------------------------------------------------

// ---------------------------------------------------------------------------
// Kernel 1: MFMA QKV projection, split-K x4, weights inlined from fp32.
// ---------------------------------------------------------------------------
__global__ __launch_bounds__(256) void qkv_mfma(
    const float* __restrict__ x,
    const float* __restrict__ Wq, const float* __restrict__ bq,
    const float* __restrict__ Wk, const float* __restrict__ bk,
    const float* __restrict__ Wv, const float* __restrict__ bv,
    __bf16* __restrict__ qbf, __bf16* __restrict__ kbf, __bf16* __restrict__ vtb)
{
    const int tid  = threadIdx.x;
    const int lane = tid & 63;
    const int w    = tid >> 6;        // 0..3 (K-quarter)
    const int lr = lane & 15;
    const int lh = lane >> 4;
    const int tok0 = blockIdx.x * 16;
    const int k0   = w * 128;

    const float qs = 0.17677669529663687f;   // 1/sqrt(32)
    const float* xp = x + (size_t)(tok0 + lr) * EMB + k0 + lh * 8;

    const float* wbase[6] = { Wq + lr, Wq + 16 + lr,
                              Wk + lr, Wk + 16 + lr,
                              Wv + lr, Wv + 16 + lr };

    auto ldfrag = [&](int f, int koff) -> bf16x8 {
        const float* p = wbase[f] + (size_t)(k0 + koff + lh * 8) * HS;
        const float s = (f < 2) ? qs : 1.0f;
        bf16x8 r;
        #pragma unroll
        for (int j = 0; j < 8; ++j)
            r[j] = (__bf16)(p[(size_t)j * HS] * s);
        return r;
    };
    auto ldx = [&](int koff) -> bf16x8 {
        const float4 a4 = *(const float4*)(xp + koff);
        const float4 b4 = *(const float4*)(xp + koff + 4);
        return bf16x8{ (__bf16)a4.x, (__bf16)a4.y, (__bf16)a4.z, (__bf16)a4.w,
                       (__bf16)b4.x, (__bf16)b4.y, (__bf16)b4.z, (__bf16)b4.w };
    };

    const f32x4 z = {0.f, 0.f, 0.f, 0.f};
    f32x4 acc[6] = {z, z, z, z, z, z};   // aq0,aq1,ak0,ak1,av0,av1

    bf16x8 xf_c, wf_c[6], xf_n, wf_n[6];
    xf_c = ldx(0);
    #pragma unroll
    for (int f = 0; f < 6; ++f) wf_c[f] = ldfrag(f, 0);

    #pragma unroll
    for (int kt = 0; kt < 128; kt += 32) {
        const int ktn = (kt + 32 < 128) ? (kt + 32) : kt;
        xf_n = ldx(ktn);
        #pragma unroll
        for (int f = 0; f < 6; ++f) wf_n[f] = ldfrag(f, ktn);

        acc[0] = __builtin_amdgcn_mfma_f32_16x16x32_bf16(wf_c[0], xf_c, acc[0], 0, 0, 0);
        acc[1] = __builtin_amdgcn_mfma_f32_16x16x32_bf16(wf_c[1], xf_c, acc[1], 0, 0, 0);
        acc[2] = __builtin_amdgcn_mfma_f32_16x16x32_bf16(wf_c[2], xf_c, acc[2], 0, 0, 0);
        acc[3] = __builtin_amdgcn_mfma_f32_16x16x32_bf16(wf_c[3], xf_c, acc[3], 0, 0, 0);
        acc[4] = __builtin_amdgcn_mfma_f32_16x16x32_bf16(xf_c, wf_c[4], acc[4], 0, 0, 0);
        acc[5] = __builtin_amdgcn_mfma_f32_16x16x32_bf16(xf_c, wf_c[5], acc[5], 0, 0, 0);

        xf_c = xf_n;
        #pragma unroll
        for (int f = 0; f < 6; ++f) wf_c[f] = wf_n[f];
    }

    __shared__ float red[3 * 6 * 256];
    if (w > 0) {
        #pragma unroll
        for (int i = 0; i < 6; ++i)
            *(f32x4*)&red[((w - 1) * 6 + i) * 256 + lane * 4] = acc[i];
    }
    __syncthreads();
    if (w != 0) return;

    #pragma unroll
    for (int i = 0; i < 6; ++i)
        #pragma unroll
        for (int ww = 0; ww < 3; ++ww)
            acc[i] += *(const f32x4*)&red[(ww * 6 + i) * 256 + lane * 4];

    #pragma unroll
    for (int f = 0; f < 2; ++f) {
        const int cb = f * 16 + lh * 4;
        const float4 bq4 = *(const float4*)(bq + cb);
        const float4 bk4 = *(const float4*)(bk + cb);
        bf16x4 oq = { (__bf16)(acc[f][0] + bq4.x * qs), (__bf16)(acc[f][1] + bq4.y * qs),
                      (__bf16)(acc[f][2] + bq4.z * qs), (__bf16)(acc[f][3] + bq4.w * qs) };
        bf16x4 ok = { (__bf16)(acc[2+f][0] + bk4.x), (__bf16)(acc[2+f][1] + bk4.y),
                      (__bf16)(acc[2+f][2] + bk4.z), (__bf16)(acc[2+f][3] + bk4.w) };
        *(bf16x4*)(qbf + (size_t)(tok0 + lr) * HS + cb) = oq;
        *(bf16x4*)(kbf + (size_t)(tok0 + lr) * HS + cb) = ok;
    }
    {
        const int b    = tok0 >> 12;
        const int t_in = (tok0 & (TSEQ - 1)) + lh * 4;
        #pragma unroll
        for (int f = 0; f < 2; ++f) {
            const int d = f * 16 + lr;
            const float bv1 = bv[d];
            bf16x4 o = { (__bf16)(acc[4+f][0] + bv1), (__bf16)(acc[4+f][1] + bv1),
                         (__bf16)(acc[4+f][2] + bv1), (__bf16)(acc[4+f][3] + bv1) };
            *(bf16x4*)(vtb + ((size_t)(b * HS + d)) * TSEQ + t_in) = o;
        }
    }
}

// ---------------------------------------------------------------------------
// Kernel 2: FUSED attention + projection (R13 structure + T5 setprio).
// ---------------------------------------------------------------------------
__device__ __forceinline__ void s_stage2(
    const bf16x8 ck0, const bf16x8 ck1,
    const bf16x8 qb0, const bf16x8 qb1,
    int kt, int q0, int lr, int lh, int swz,
    float lp[2], char* Pb)
{
    const f32x4 z = {0.f, 0.f, 0.f, 0.f};
    __builtin_amdgcn_s_setprio(1);
    f32x4 st00 = __builtin_amdgcn_mfma_f32_16x16x32_bf16(ck0, qb0, z, 0, 0, 0);
    f32x4 st01 = __builtin_amdgcn_mfma_f32_16x16x32_bf16(ck1, qb0, z, 0, 0, 0);
    f32x4 st10 = __builtin_amdgcn_mfma_f32_16x16x32_bf16(ck0, qb1, z, 0, 0, 0);
    f32x4 st11 = __builtin_amdgcn_mfma_f32_16x16x32_bf16(ck1, qb1, z, 0, 0, 0);
    __builtin_amdgcn_s_setprio(0);

    float P[2][2][4];   // [qh][kh][r]; key_l = kh*16+lh*4+r, q_l = qh*16+lr
    #pragma unroll
    for (int r = 0; r < 4; ++r) {
        P[0][0][r] = st00[r]; P[0][1][r] = st01[r];
        P[1][0][r] = st10[r]; P[1][1][r] = st11[r];
    }

    if (kt != q0) {
        #pragma unroll
        for (int qh = 0; qh < 2; ++qh)
            #pragma unroll
            for (int kh = 0; kh < 2; ++kh)
                #pragma unroll
                for (int r = 0; r < 4; ++r)
                    P[qh][kh][r] = __expf(P[qh][kh][r]);
    } else {
        #pragma unroll
        for (int qh = 0; qh < 2; ++qh)
            #pragma unroll
            for (int kh = 0; kh < 2; ++kh)
                #pragma unroll
                for (int r = 0; r < 4; ++r) {
                    const int key_l = kh * 16 + lh * 4 + r;
                    const int q_l   = qh * 16 + lr;
                    P[qh][kh][r] = (key_l <= q_l) ? __expf(P[qh][kh][r]) : 0.f;
                }
    }

    #pragma unroll
    for (int qh = 0; qh < 2; ++qh)
        #pragma unroll
        for (int kh = 0; kh < 2; ++kh)
            #pragma unroll
            for (int r = 0; r < 4; ++r)
                lp[qh] += P[qh][kh][r];

    #pragma unroll
    for (int qh = 0; qh < 2; ++qh)
        #pragma unroll
        for (int kh = 0; kh < 2; ++kh) {
            const int q    = qh * 16 + lr;
            const int byte = q * 128 + ((kh * 32 + lh * 8) ^ swz);
            bf16x4 pk = { (__bf16)P[qh][kh][0], (__bf16)P[qh][kh][1],
                          (__bf16)P[qh][kh][2], (__bf16)P[qh][kh][3] };
            *(bf16x4*)(Pb + byte) = pk;
        }
}

__device__ __forceinline__ void strip_proc2(
    int kt0, int kend, int q0,
    const bf16x8 qb0, const bf16x8 qb1,
    const __bf16* kbase, const __bf16* vbase,
    char* Pl,
    f32x4 o[4], float lp[2],
    int lr, int lh, int swz, int rdA, int rdB)
{
    if (kt0 >= kend) return;

    bf16x8 kf0 = *(const bf16x8*)(kbase + (size_t)kt0 * HS);
    bf16x8 kf1 = *(const bf16x8*)(kbase + (size_t)(kt0 + 16) * HS);
    bf16x8 vf0 = *(const bf16x8*)(vbase + kt0);
    bf16x8 vf1 = *(const bf16x8*)(vbase + kt0 + 16 * TSEQ);

    bf16x8 cv0p, cv1p;
    int pb = 1;
    {
        const bf16x8 ck0 = kf0, ck1 = kf1;
        cv0p = vf0; cv1p = vf1;
        const int ktn = (kt0 + 256 < kend) ? (kt0 + 256) : kt0;
        kf0 = *(const bf16x8*)(kbase + (size_t)ktn * HS);
        kf1 = *(const bf16x8*)(kbase + (size_t)(ktn + 16) * HS);
        vf0 = *(const bf16x8*)(vbase + ktn);
        vf1 = *(const bf16x8*)(vbase + ktn + 16 * TSEQ);
        s_stage2(ck0, ck1, qb0, qb1, kt0, q0, lr, lh, swz, lp, Pl);
    }

    for (int kt = kt0 + 256; kt < kend; kt += 256) {
        const bf16x8 ck0 = kf0, ck1 = kf1, cv0 = vf0, cv1 = vf1;
        const int ktn = (kt + 256 < kend) ? (kt + 256) : kt;
        kf0 = *(const bf16x8*)(kbase + (size_t)ktn * HS);
        kf1 = *(const bf16x8*)(kbase + (size_t)(ktn + 16) * HS);
        vf0 = *(const bf16x8*)(vbase + ktn);
        vf1 = *(const bf16x8*)(vbase + ktn + 16 * TSEQ);

        const char* pbase = Pl + (pb ^ 1) * 4096;
        const bf16x8 pa0 = *(const bf16x8*)(pbase + rdA);
        const bf16x8 pa1 = *(const bf16x8*)(pbase + rdB);

        s_stage2(ck0, ck1, qb0, qb1, kt, q0, lr, lh, swz, lp, Pl + pb * 4096);

        __builtin_amdgcn_s_setprio(1);
        o[0] = __builtin_amdgcn_mfma_f32_16x16x32_bf16(pa0, cv0p, o[0], 0, 0, 0);
        o[1] = __builtin_amdgcn_mfma_f32_16x16x32_bf16(pa0, cv1p, o[1], 0, 0, 0);
        o[2] = __builtin_amdgcn_mfma_f32_16x16x32_bf16(pa1, cv0p, o[2], 0, 0, 0);
        o[3] = __builtin_amdgcn_mfma_f32_16x16x32_bf16(pa1, cv1p, o[3], 0, 0, 0);
        __builtin_amdgcn_s_setprio(0);

        cv0p = cv0; cv1p = cv1; pb ^= 1;
    }

    {
        const char* pbase = Pl + (pb ^ 1) * 4096;
        const bf16x8 pa0 = *(const bf16x8*)(pbase + rdA);
        const bf16x8 pa1 = *(const bf16x8*)(pbase + rdB);
        __builtin_amdgcn_s_setprio(1);
        o[0] = __builtin_amdgcn_mfma_f32_16x16x32_bf16(pa0, cv0p, o[0], 0, 0, 0);
        o[1] = __builtin_amdgcn_mfma_f32_16x16x32_bf16(pa0, cv1p, o[1], 0, 0, 0);
        o[2] = __builtin_amdgcn_mfma_f32_16x16x32_bf16(pa1, cv0p, o[2], 0, 0, 0);
        o[3] = __builtin_amdgcn_mfma_f32_16x16x32_bf16(pa1, cv1p, o[3], 0, 0, 0);
        __builtin_amdgcn_s_setprio(0);
    }
}

__global__ __launch_bounds__(512) void attn_fused(
    const __bf16* __restrict__ qbf, const __bf16* __restrict__ kbf,
    const __bf16* __restrict__ vtb,
    const float* __restrict__ Wp, const float* __restrict__ bp,
    float* __restrict__ out)
{
    const int p   = blockIdx.x;       // strips p and 127-p
    const int b   = blockIdx.y;
    const int tid = threadIdx.x;
    const int w    = tid >> 6;        // 0..7
    const int lane = tid & 63;
    const int lr = lane & 15;
    const int lh = lane >> 4;

    const int n0  = p + 1;
    const int q00 = p * 32;
    const int q01 = (127 - p) * 32;

    extern __shared__ char smem[];
    char*   myPl   = smem + w * 8192;
    float*  red    = (float*)smem;
    float*  lpred  = (float*)(smem + 65536);
    __bf16* attn_s = (__bf16*)(smem + 65536 + 2048);

    const __bf16* qp0 = qbf + ((size_t)(b * TSEQ + q00 + lr)) * HS + lh * 8;
    const __bf16* qp1 = qbf + ((size_t)(b * TSEQ + q01 + lr)) * HS + lh * 8;
    const bf16x8 qb0s0 = *(const bf16x8*)qp0;
    const bf16x8 qb1s0 = *(const bf16x8*)(qp0 + 16 * HS);
    const bf16x8 qb0s1 = *(const bf16x8*)qp1;
    const bf16x8 qb1s1 = *(const bf16x8*)(qp1 + 16 * HS);

    const __bf16* kbase = kbf + ((size_t)(b * TSEQ + lr)) * HS + lh * 8;
    const __bf16* vbase = vtb + (size_t)(b * HS + lr) * TSEQ + lh * 8;

    const int swz = (lr & 7) << 4;
    const int rdA = lr * 128 + ((lh * 16) ^ swz);
    const int rdB = (16 + lr) * 128 + ((lh * 16) ^ swz);

    const f32x4 z = {0.f, 0.f, 0.f, 0.f};
    f32x4 o0[4] = {z, z, z, z};
    f32x4 o1[4] = {z, z, z, z};
    float lp0[2] = {0.f, 0.f}, lp1[2] = {0.f, 0.f};

    strip_proc2(w * 32, q00 + 32, q00, qb0s0, qb1s0, kbase, vbase, myPl,
                o0, lp0, lr, lh, swz, rdA, rdB);
    const int tb = n0 + ((w - n0) & 7);
    strip_proc2((tb - n0) * 32, q01 + 32, q01, qb0s1, qb1s1, kbase, vbase, myPl,
                o1, lp1, lr, lh, swz, rdA, rdB);

    #pragma unroll
    for (int qh = 0; qh < 2; ++qh) {
        lp0[qh] += __shfl_xor(lp0[qh], 16, 64);
        lp0[qh] += __shfl_xor(lp0[qh], 32, 64);
        lp1[qh] += __shfl_xor(lp1[qh], 16, 64);
        lp1[qh] += __shfl_xor(lp1[qh], 32, 64);
    }

    __syncthreads();

    #pragma unroll
    for (int f = 0; f < 4; ++f) {
        *(f32x4*)&red[((w * 2 + 0) * 4 + f) * 256 + lane * 4] = o0[f];
        *(f32x4*)&red[((w * 2 + 1) * 4 + f) * 256 + lane * 4] = o1[f];
    }
    if (lh == 0) {
        #pragma unroll
        for (int qh = 0; qh < 2; ++qh) {
            lpred[(w * 2 + 0) * 32 + qh * 16 + lr] = lp0[qh];
            lpred[(w * 2 + 1) * 32 + qh * 16 + lr] = lp1[qh];
        }
    }
    __syncthreads();

    {
        const int s  = w >> 2;
        const int f  = w & 3;
        const int qh = f >> 1;
        const int dh = f & 1;
        f32x4 sum = z;
        #pragma unroll
        for (int ww = 0; ww < 8; ++ww)
            sum += *(const f32x4*)&red[((ww * 2 + s) * 4 + f) * 256 + lane * 4];

        #pragma unroll
        for (int r = 0; r < 4; ++r) {
            const int q = qh * 16 + lh * 4 + r;
            float L = 0.f;
            #pragma unroll
            for (int ww = 0; ww < 8; ++ww)
                L += lpred[(ww * 2 + s) * 32 + q];
            attn_s[(s * 32 + q) * 32 + dh * 16 + lr] = (__bf16)(sum[r] / L);
        }
    }
    __syncthreads();

    // projection (SWAPPED): wave w -> strip sp = w>>2, cols [(w&3)*128, +128)
    {
        const int sp = w >> 2;
        const int c0 = (w & 3) * 128;
        const int qb0i = (sp == 0) ? q00 : q01;
        const __bf16* as = attn_s + sp * 1024;
        const bf16x8 a0 = *(const bf16x8*)(as + lr * 32 + lh * 8);
        const bf16x8 a1 = *(const bf16x8*)(as + (16 + lr) * 32 + lh * 8);

        #pragma unroll
        for (int g = 0; g < 8; ++g) {
            const int c = c0 + g * 16;
            const float* wsrc = Wp + (size_t)(lh * 8) * EMB + c + lr;
            bf16x8 wa;
            #pragma unroll
            for (int j = 0; j < 8; ++j)
                wa[j] = (__bf16)wsrc[(size_t)j * EMB];

            f32x4 d0 = __builtin_amdgcn_mfma_f32_16x16x32_bf16(wa, a0, z, 0, 0, 0);
            f32x4 d1 = __builtin_amdgcn_mfma_f32_16x16x32_bf16(wa, a1, z, 0, 0, 0);

            const float4 b4 = *(const float4*)(bp + c + lh * 4);
            const float4 ov0 = make_float4(d0[0] + b4.x, d0[1] + b4.y,
                                           d0[2] + b4.z, d0[3] + b4.w);
            const float4 ov1 = make_float4(d1[0] + b4.x, d1[1] + b4.y,
                                           d1[2] + b4.z, d1[3] + b4.w);
            *(float4*)(out + (size_t)(b * TSEQ + qb0i + lr)      * EMB + c + lh * 4) = ov0;
            *(float4*)(out + (size_t)(b * TSEQ + qb0i + 16 + lr) * EMB + c + lh * 4) = ov1;
        }
    }
}

// ---------------------------------------------------------------------------
extern "C" void kernel_launch(void* const* d_in, const int* in_sizes, int n_in,
                              void* d_out, int out_size, void* d_ws, size_t ws_size,
                              hipStream_t stream)
{
    const float* x  = (const float*)d_in[0];
    const float* Wq = (const float*)d_in[1];
    const float* bq = (const float*)d_in[2];
    const float* Wk = (const float*)d_in[3];
    const float* bk = (const float*)d_in[4];
    const float* Wv = (const float*)d_in[5];
    const float* bv = (const float*)d_in[6];
    const float* Wp = (const float*)d_in[7];
    const float* bp = (const float*)d_in[8];
    float* out = (float*)d_out;

    // workspace: qbf @0 (1MB), kbf @1MB (1MB), vtb @2MB (1MB)
    char* ws = (char*)d_ws;
    __bf16* qbf = (__bf16*)(ws);
    __bf16* kbf = (__bf16*)(ws + (size_t)1 * 1024 * 1024);
    __bf16* vtb = (__bf16*)(ws + (size_t)2 * 1024 * 1024);

    qkv_mfma<<<dim3(NQ / 16), 256, 0, stream>>>(x, Wq, bq, Wk, bk, Wv, bv,
                                                qbf, kbf, vtb);
    attn_fused<<<dim3(64, NB), 512, 71680, stream>>>(qbf, kbf, vtb, Wp, bp, out);
}